// Round 6
// baseline (25.565 us; speedup 1.0000x reference)
//
#include <hip/hip_runtime.h>
#include <float.h>

#define BB 32
#define CC 128
#define HH 64
#define WW 64
#define NCH 4   // channels per block; each wave handles all 4 channels for 2 bins

// Block = 256 threads = 4 waves; block covers 4 channels of one (b, lmi).
// Wave w computes row-bins {2w, 2w+1} for all 4 channels (16 loads in flight).
// Grid = 32*8*32 = 8192, ordered b-fastest so XCD = b%8 (per-XCD L2 ~3.4MB fits).
__global__ __launch_bounds__(256) void roipool_kernel(
    const float* __restrict__ x,   // [B,C,64,64]
    const float* __restrict__ lm,  // [B,16]
    float* __restrict__ out)       // [B,C,32,16]
{
    int blk = blockIdx.x;
    int b   = blk & 31;          // fastest -> XCD round-robin by batch
    int lmi = (blk >> 5) & 7;
    int cg  = blk >> 8;          // 0..31 channel group

    int tid  = threadIdx.x;
    int wave = tid >> 6;
    int lane = tid & 63;

    __shared__ float s[NCH][8][65];   // padded

    float x0 = lm[b * 16 + 2 * lmi];
    float y0 = lm[b * 16 + 2 * lmi + 1];
    bool visible = (x0 > 0.0f) || (y0 > 0.0f);

    // torchvision column-swap semantics:
    // rois=(b,x1,x2,y1,y2) consumed as (b,start_w,start_h,end_w,end_h)
    int fx = (int)floorf(x0 * 0.25f);
    int fy = (int)floorf(y0 * 0.25f);
    int roi = max(fy - fx + 1, 1);      // roi_w == roi_h
    float bin = (float)roi * 0.125f;    // exact /8

    int cbase = cg * NCH;

    // thread = (ch, cell i, cell j) for fast path + stage 2
    int ch = wave;
    int i  = lane >> 3;
    int j  = lane & 7;
    int orow = 8 * (lmi >> 1) + i;
    int ocol = 8 * (lmi & 1) + j;
    size_t obase = (((size_t)b * CC + cbase + ch) * 32 + orow) * 16 + ocol;

    // ---------- fast path: roi==1 -> every cell is pixel (fx, fx-7) ----------
    if (roi == 1) {
        int hs = min(max(fx, 0), HH),     he = min(max(fx + 1, 0), HH);
        int ws = min(max(fx - 7, 0), WW), we = min(max(fx - 6, 0), WW);
        bool empty = (he <= hs) || (we <= ws) || !visible;
        float v = 0.0f;
        if (!empty) v = x[(((size_t)b * CC + cbase + ch) << 12) + (hs << 6) + ws];
        out[obase] = empty ? 0.0f : v;
        return;   // block-uniform branch
    }

    // clipped column window
    int w0 = max(fx - 7, 0);
    int w1 = min(fx - 7 + roi, WW);

    const float* __restrict__ p0 = x + (((size_t)b * CC + cbase) << 12) + lane;
    const float* __restrict__ p1 = p0 + (1 << 12);
    const float* __restrict__ p2 = p0 + (2 << 12);
    const float* __restrict__ p3 = p0 + (3 << 12);

    // ---------- stage 1: wave w -> bins 2w,2w+1 for all 4 channels ----------
    // lane = absolute column; mask out-of-window lanes (no lines fetched for them)
    if (visible && lane >= w0 && lane < w1) {
        #pragma unroll
        for (int tt = 0; tt < 2; ++tt) {
            int t = 2 * wave + tt;
            int hs = min(max((int)floorf((float)t * bin) + fx, 0), HH);
            int he = min(max((int)ceilf((float)(t + 1) * bin) + fx, 0), HH);
            float m0 = -FLT_MAX, m1 = -FLT_MAX, m2 = -FLT_MAX, m3 = -FLT_MAX;
            for (int h = hs; h < he; h += 4) {
                // clamped duplicate rows are harmless under max; 16 loads in flight
                int ha = min(h + 1, he - 1);
                int hb = min(h + 2, he - 1);
                int hc = min(h + 3, he - 1);
                float a0 = p0[h << 6], a1 = p0[ha << 6], a2 = p0[hb << 6], a3 = p0[hc << 6];
                float b0 = p1[h << 6], b1 = p1[ha << 6], b2 = p1[hb << 6], b3 = p1[hc << 6];
                float c0 = p2[h << 6], c1 = p2[ha << 6], c2 = p2[hb << 6], c3 = p2[hc << 6];
                float d0 = p3[h << 6], d1 = p3[ha << 6], d2 = p3[hb << 6], d3 = p3[hc << 6];
                m0 = fmaxf(m0, fmaxf(fmaxf(a0, a1), fmaxf(a2, a3)));
                m1 = fmaxf(m1, fmaxf(fmaxf(b0, b1), fmaxf(b2, b3)));
                m2 = fmaxf(m2, fmaxf(fmaxf(c0, c1), fmaxf(c2, c3)));
                m3 = fmaxf(m3, fmaxf(fmaxf(d0, d1), fmaxf(d2, d3)));
            }
            s[0][t][lane] = m0;
            s[1][t][lane] = m1;
            s[2][t][lane] = m2;
            s[3][t][lane] = m3;
        }
    }
    __syncthreads();

    // ---------- stage 2: pool columns from LDS; thread = (ch, i, j) ----------
    int hs = min(max((int)floorf((float)i * bin) + fx, 0), HH);
    int he = min(max((int)ceilf((float)(i + 1) * bin) + fx, 0), HH);
    int ws = min(max((int)floorf((float)j * bin) + fx - 7, 0), WW);
    int we = min(max((int)ceilf((float)(j + 1) * bin) + fx - 7, 0), WW);
    bool empty = (he <= hs) || (we <= ws) || !visible;

    float m = -FLT_MAX;
    if (!empty) {
        for (int w = ws; w < we; ++w)   // [ws,we) is within [w0,w1): s was written there
            m = fmaxf(m, s[ch][i][w]);
    }
    out[obase] = empty ? 0.0f : m;
}

extern "C" void kernel_launch(void* const* d_in, const int* in_sizes, int n_in,
                              void* d_out, int out_size, void* d_ws, size_t ws_size,
                              hipStream_t stream) {
    const float* x  = (const float*)d_in[0];
    const float* lm = (const float*)d_in[1];
    float* out = (float*)d_out;

    int blocks = BB * 8 * (CC / NCH);   // 8192
    roipool_kernel<<<blocks, 256, 0, stream>>>(x, lm, out);
}